// Round 7
// baseline (224.598 us; speedup 1.0000x reference)
//
#include <hip/hip_runtime.h>
#include <hip/hip_bf16.h>
#include <math.h>

// B=8, H=W=128, CH=64, OC=64, NCA_C=128, K=3, dils {1,2,4,8}, HID=64
// out: y [8,128,128,64] fp32 (8388608) then c2 [8,64] fp32 (512)
//
// Depthwise conv folded into GEMM1 over 33 positions (center-merged: identity + 4
// dilation centers share A data -> one U). Wave-private LDS row buffers share A
// across dx shifts (9 rows instead of 33 loads) -- NO barriers in K-loop (round 6
// showed chunk barriers cost ~22us). B (U) per-wave from global (L1-shared).
// b = blk&7 -> XCD-local L2.

typedef float  f32x4 __attribute__((ext_vector_type(4)));
typedef short  s16x8 __attribute__((ext_vector_type(8)));

static __device__ __forceinline__ unsigned short f2bf(float f) {
    __hip_bfloat16 h = __float2bfloat16(f);
    unsigned short u; __builtin_memcpy(&u, &h, 2); return u;
}

// xpad layout: [b][plane(4)][yy(144)][xx(144)][16ch] bf16
#define XROW   2304
#define XPLANE 331776
#define XBATCH 1327104

// ---------------- prepA: x -> padded bf16, pad zero-fill, c2 ----------------
__global__ void prepA(const float* __restrict__ x, const float* __restrict__ c,
                      const float* __restrict__ Wv, const float* __restrict__ bv,
                      const float* __restrict__ Wo, const float* __restrict__ bo,
                      const float* __restrict__ lng, const float* __restrict__ lnb,
                      unsigned short* __restrict__ xp, float* __restrict__ c2f,
                      float* __restrict__ outc2)
{
    const int blk = blockIdx.x, tid = threadIdx.x;
    if (blk < 512) {
        int i = blk*256 + tid;               // px index [0,131072)
        int xc = i & 127, y = (i >> 7) & 127, b = i >> 14;
        const float* src = x + (size_t)i*64;
        unsigned short* dstb = xp + ((size_t)b*4*144 + (y+8))*XROW + (xc+8)*16;
        #pragma unroll
        for (int p = 0; p < 4; ++p) {
            float4 f0 = *(const float4*)(src + p*16 + 0);
            float4 f1 = *(const float4*)(src + p*16 + 4);
            float4 f2 = *(const float4*)(src + p*16 + 8);
            float4 f3 = *(const float4*)(src + p*16 + 12);
            uint4 o0, o1;
            o0.x = (unsigned)f2bf(f0.x) | ((unsigned)f2bf(f0.y) << 16);
            o0.y = (unsigned)f2bf(f0.z) | ((unsigned)f2bf(f0.w) << 16);
            o0.z = (unsigned)f2bf(f1.x) | ((unsigned)f2bf(f1.y) << 16);
            o0.w = (unsigned)f2bf(f1.z) | ((unsigned)f2bf(f1.w) << 16);
            o1.x = (unsigned)f2bf(f2.x) | ((unsigned)f2bf(f2.y) << 16);
            o1.y = (unsigned)f2bf(f2.z) | ((unsigned)f2bf(f2.w) << 16);
            o1.z = (unsigned)f2bf(f3.x) | ((unsigned)f2bf(f3.y) << 16);
            o1.w = (unsigned)f2bf(f3.z) | ((unsigned)f2bf(f3.w) << 16);
            unsigned short* d = dstb + (size_t)p*XPLANE;
            *(uint4*)d = o0; *(uint4*)(d + 8) = o1;
        }
    } else if (blk < 1056) {
        int idx = (blk - 512)*256 + tid;     // [0,139264) pad px
        int bp = idx / 4352;                 // b*4+plane
        int r  = idx - bp*4352;
        int yy, xx;
        if (r < 2304) { int ry = r / 144; xx = r - ry*144; yy = (ry < 8) ? ry : 128 + ry; }
        else { int r2 = r - 2304; yy = 8 + (r2 >> 4); int xi = r2 & 15; xx = (xi < 8) ? xi : 128 + xi; }
        uint4 z = make_uint4(0,0,0,0);
        unsigned short* d = xp + ((size_t)bp*144 + yy)*XROW + xx*16;
        *(uint4*)d = z; *(uint4*)(d + 8) = z;
    } else {
        // c2 = c + LN(v@Wo + bo + c), v = c@Wv + bv  (softmax pool == v exactly)
        const int b = blk - 1056;
        __shared__ float sc[64], sv[64];
        const int j = tid;
        if (j < 64) sc[j] = c[b*64 + j];
        __syncthreads();
        if (j < 64) {
            float v = bv[j];
            for (int i = 0; i < 64; ++i) v += sc[i]*Wv[i*64 + j];
            sv[j] = v;
        }
        __syncthreads();
        if (j < 64) {
            float t = bo[j] + sc[j];
            for (int i = 0; i < 64; ++i) t += sv[i]*Wo[i*64 + j];
            float s = t;
            for (int o = 32; o > 0; o >>= 1) s += __shfl_xor(s, o);
            float m = s * (1.f/64.f);
            float dq = (t - m)*(t - m);
            for (int o = 32; o > 0; o >>= 1) dq += __shfl_xor(dq, o);
            float a = (t - m) / sqrtf(dq*(1.f/64.f) + 1e-5f) * lng[j] + lnb[j];
            float c2 = sc[j] + a;
            c2f[b*64 + j] = c2;
            outc2[b*64 + j] = c2;
        }
    }
}

// ---------------- prepB: U frags (33 pos, row-grouped order), W2, V, hcp ----
// position order: g0..g3 rows dy=-8,-4,-2,-1 (dx=-d,0,+d); p12 = merged center
// (identity + 4 dil centers); p13..20 dy=0 dx=+-1,+-2,+-4,+-8; g5..g8 dy=+1,+2,+4,+8.
__global__ void prepB(const float* __restrict__ pk, const float* __restrict__ W1,
                      const float* __restrict__ W2, const float* __restrict__ b1,
                      const float* __restrict__ c2f,
                      unsigned short* __restrict__ Uf, unsigned short* __restrict__ W2s,
                      float* __restrict__ V, float* __restrict__ hcp)
{
    const int blk = blockIdx.x, tid = threadIdx.x;
    if (blk < 66) {
        int idx = blk*256 + tid;            // [0, 16896) = 33*512
        int lane = idx & 63, nt = (idx >> 6) & 3, kc2 = (idx >> 8) & 1, pos = idx >> 9;
        int n  = nt*16 + (lane & 15);
        int k0 = kc2*32 + (lane >> 4)*8;
        static constexpr int DI[33] = {3,3,3, 2,2,2, 1,1,1, 0,0,0, -1, 0,0, 1,1, 2,2, 3,3,
                                       0,0,0, 1,1,1, 2,2,2, 3,3,3};
        static constexpr int TT[33] = {0,1,2, 0,1,2, 0,1,2, 0,1,2, 4, 3,5, 3,5, 3,5, 3,5,
                                       6,7,8, 6,7,8, 6,7,8, 6,7,8};
        int di = DI[pos], t = TT[pos];
        unsigned short e[8];
        #pragma unroll
        for (int j = 0; j < 8; ++j) {
            int ch = k0 + j;
            float v;
            if (di < 0) {
                v = W1[ch*64 + n];
                for (int dd = 0; dd < 4; ++dd)
                    v += pk[(dd*128 + ch)*9 + 4] * W1[((1+dd)*128 + ch)*64 + n];
            } else {
                v = pk[(di*128 + ch)*9 + t] * W1[((1+di)*128 + ch)*64 + n];
            }
            e[j] = f2bf(v);
        }
        uint4 o;
        o.x = (unsigned)e[0] | ((unsigned)e[1] << 16);
        o.y = (unsigned)e[2] | ((unsigned)e[3] << 16);
        o.z = (unsigned)e[4] | ((unsigned)e[5] << 16);
        o.w = (unsigned)e[6] | ((unsigned)e[7] << 16);
        *(uint4*)(Uf + (size_t)idx*8) = o;
    } else if (blk < 68) {
        int idx = (blk-66)*256 + tid;       // [0,512)
        int lane = idx & 63, nt = (idx >> 6) & 3, kc2 = (idx >> 8) & 1;
        int n  = nt*16 + (lane & 15);
        int k0 = kc2*32 + (lane >> 4)*8;
        unsigned short e[8];
        #pragma unroll
        for (int j = 0; j < 8; ++j) e[j] = f2bf(W2[(k0+j)*64 + n]);
        uint4 o;
        o.x = (unsigned)e[0] | ((unsigned)e[1] << 16);
        o.y = (unsigned)e[2] | ((unsigned)e[3] << 16);
        o.z = (unsigned)e[4] | ((unsigned)e[5] << 16);
        o.w = (unsigned)e[6] | ((unsigned)e[7] << 16);
        *(uint4*)(W2s + (size_t)idx*8) = o;
    } else if (blk < 140) {
        int idx = (blk-68)*256 + tid;       // [0, 18432) = 8*36*64
        int n = idx & 63, q = idx >> 6;     // q = b*36 + p
        int p = q % 36, b = q / 36;
        int di = p/9, t = p%9;
        float s = 0.f;
        for (int j = 0; j < 64; ++j)
            s += c2f[b*64 + j] * pk[(di*128 + 64 + j)*9 + t] * W1[((1+di)*128 + 64 + j)*64 + n];
        V[(size_t)q*64 + n] = s;
    } else {
        for (int it = tid; it < 512; it += 256) {
            int b = it >> 6, n = it & 63;
            float s = b1[n];
            for (int j = 0; j < 64; ++j) s += c2f[b*64 + j]*W1[(64 + j)*64 + n];
            hcp[it] = s;
        }
    }
}

// ---------------- main fused kernel -----------------------------------------
#define HID_S 72
#define PXS   72        // LDS shorts per px (64 ch + 8 pad -> 2-way banks max)
#define WBUF  (96*PXS)  // 6912 shorts (13,824 B) per wave row buffer

__global__ __launch_bounds__(256) void nca_main(
    const unsigned short* __restrict__ xp,
    const unsigned short* __restrict__ U,
    const unsigned short* __restrict__ W2s,
    const float* __restrict__ V,
    const float* __restrict__ hcp,
    const float* __restrict__ b2,
    float* __restrict__ out)
{
    __shared__ unsigned short rowbuf[4*WBUF]; // 55,296 B; reused as hid[256][72] after K-loop
    __shared__ float V_l[36*64];              //  9216 B
    __shared__ float Cx_l[16*64];             //  4096 B
    __shared__ float Cy_l[2*64];              //   512 B
    __shared__ float hc2_l[64];               //   256 B  -> total 69,376 B (2 blocks/CU)

    const int tid = threadIdx.x;
    const int blk = blockIdx.x;
    const int b  = blk & 7;                   // XCD-local batch
    const int y0 = (blk >> 3) * 2;
    const int lane = tid & 63;
    const int w    = tid >> 6;

    // ---- tables ----
    {
        const float4* Vg = (const float4*)(V + (size_t)b*2304);
        for (int i = tid; i < 576; i += 256) ((float4*)V_l)[i] = Vg[i];
    }
    __syncthreads();
    for (int it = tid; it < 1024; it += 256) {      // Cx: x-edge correction
        int xi = it >> 6, n = it & 63;
        int xx = xi < 8 ? xi : 112 + xi;
        float s = 0.f;
        #pragma unroll
        for (int di = 0; di < 4; ++di) {
            int d = 1 << di;
            int dxo = (xx < d) ? 0 : ((xx >= 128 - d) ? 2 : -1);
            if (dxo >= 0) {
                s += V_l[(di*9 + 0*3 + dxo)*64 + n];
                s += V_l[(di*9 + 1*3 + dxo)*64 + n];
                s += V_l[(di*9 + 2*3 + dxo)*64 + n];
            }
        }
        Cx_l[it] = s;
    }
    for (int it = tid; it < 128; it += 256) {       // Cy for this block's 2 rows
        int r = it >> 6, n = it & 63;
        int yy = y0 + r;
        float s = 0.f;
        #pragma unroll
        for (int di = 0; di < 4; ++di) {
            int d = 1 << di;
            int dyo = (yy < d) ? 0 : ((yy >= 128 - d) ? 2 : -1);
            if (dyo >= 0) {
                s += V_l[(di*9 + dyo*3 + 0)*64 + n];
                s += V_l[(di*9 + dyo*3 + 1)*64 + n];
                s += V_l[(di*9 + dyo*3 + 2)*64 + n];
            }
        }
        Cy_l[it] = s;
    }
    if (tid < 64) {
        float s = hcp[b*64 + tid];
        for (int p = 0; p < 36; ++p) s += V_l[p*64 + tid];
        hc2_l[tid] = s;
    }
    __syncthreads();

    // ---- geometry ----
    const int y    = y0 + (w >> 1);
    const int xw   = (w & 1) * 64;
    const int ln15 = lane & 15;
    const int oct  = lane >> 4;

    // ---- wave-private row staging (global -> regs -> LDS, padded px stride) ----
    const unsigned short* xb = xp + (size_t)b*XBATCH + (size_t)(xw)*16;
    uint4 rg[12];
    auto loadrow = [&](int dy) {
        const unsigned short* rs = xb + (size_t)(y + 8 + dy)*XROW;
        #pragma unroll
        for (int pl = 0; pl < 4; ++pl)
            #pragma unroll
            for (int k = 0; k < 3; ++k)
                rg[pl*3 + k] = *(const uint4*)(rs + (size_t)pl*XPLANE + (k*64 + lane)*8);
    };
    unsigned short* wbp = rowbuf + w*WBUF;
    auto writerow = [&]() {
        #pragma unroll
        for (int pl = 0; pl < 4; ++pl)
            #pragma unroll
            for (int k = 0; k < 3; ++k) {
                int e = k*64 + lane;
                *(uint4*)(wbp + (e >> 1)*PXS + pl*16 + (e & 1)*8) = rg[pl*3 + k];
            }
    };

    static constexpr int DYR[9]  = {-8,-4,-2,-1,0,1,2,4,8};
    static constexpr int PST[9]  = {0,3,6,9,12,21,24,27,30};
    static constexpr int DXOS[33] = {-576,0,576, -288,0,288, -144,0,144, -72,0,72,
                                     0, -72,72, -144,144, -288,288, -576,576,
                                     -72,0,72, -144,0,144, -288,0,288, -576,0,576};

    loadrow(-8);
    writerow();

    f32x4 acc[4][4];
    #pragma unroll
    for (int mt = 0; mt < 4; ++mt)
        #pragma unroll
        for (int nt = 0; nt < 4; ++nt) {
            acc[mt][nt][0] = 0.f; acc[mt][nt][1] = 0.f;
            acc[mt][nt][2] = 0.f; acc[mt][nt][3] = 0.f;
        }

    const unsigned short* abase = wbp + (8 + ln15)*PXS + oct*8;

    #pragma unroll 1
    for (int g = 0; g < 9; ++g) {
        if (g < 8) loadrow(DYR[g + 1]);          // reg prefetch of next row
        const int ps = PST[g];
        const int np = (g == 4) ? 9 : 3;
        #pragma unroll 1
        for (int pi = 0; pi < np; ++pi) {
            const int p = ps + pi;
            const unsigned short* ap = abase + DXOS[p];
            s16x8 av[2][4];
            #pragma unroll
            for (int kc2 = 0; kc2 < 2; ++kc2)
                #pragma unroll
                for (int mt = 0; mt < 4; ++mt)
                    av[kc2][mt] = *(const s16x8*)(ap + kc2*32 + mt*(16*PXS));
            const unsigned short* Up = U + (size_t)p*4096 + lane*8;
            #pragma unroll
            for (int kc2 = 0; kc2 < 2; ++kc2) {
                #pragma unroll
                for (int nt = 0; nt < 4; ++nt) {
                    s16x8 bf = *(const s16x8*)(Up + kc2*2048 + nt*512);
                    #pragma unroll
                    for (int mt = 0; mt < 4; ++mt)
                        acc[mt][nt] = __builtin_amdgcn_mfma_f32_16x16x32_bf16(av[kc2][mt], bf, acc[mt][nt], 0, 0, 0);
                }
            }
        }
        if (g < 8) writerow();                   // same-wave LDS order: reads above done
    }
    __syncthreads();   // all waves done with rowbuf -> safe to alias as hid

    // ---- epilogue 1: + hc2 - corrections, GELU, write hid (bf16) ----
    unsigned short* hid = rowbuf;             // [256][HID_S]
    const bool yedge = (y < 8) || (y >= 120);
    #pragma unroll
    for (int mt = 0; mt < 4; ++mt) {
        #pragma unroll
        for (int nt = 0; nt < 4; ++nt) {
            const int n = nt*16 + ln15;
            const float hcv = hc2_l[n];
            const float cyv = yedge ? Cy_l[(w >> 1)*64 + n] : 0.f;
            #pragma unroll
            for (int r = 0; r < 4; ++r) {
                int m = oct*4 + r;                  // C row = (lane>>4)*4 + reg
                int x = xw + mt*16 + m;
                float h = acc[mt][nt][r] + hcv - cyv;
                if (x < 8 || x >= 120) {
                    int xi = (x < 8) ? x : (x - 112);
                    h -= Cx_l[xi*64 + n];
                    if (yedge) {                    // corner double-subtract fix
                        #pragma unroll
                        for (int di = 0; di < 4; ++di) {
                            int d = 1 << di;
                            int dyo = (y < d) ? 0 : ((y >= 128 - d) ? 2 : -1);
                            int dxo = (x < d) ? 0 : ((x >= 128 - d) ? 2 : -1);
                            if (dyo >= 0 && dxo >= 0)
                                h += V_l[(di*9 + dyo*3 + dxo)*64 + n];
                        }
                    }
                }
                float u = 0.7978845608028654f * (h + 0.044715f*h*h*h);
                float gl = h / (1.f + __expf(-2.f*u));
                hid[(w*64 + mt*16 + m)*HID_S + n] = f2bf(gl);
            }
        }
    }
    // each wave reads back only its own 64 hid rows -> no barrier needed

    // ---- GEMM2: y = hid @ W2 + b2 ----
    f32x4 acc2[4][4];
    #pragma unroll
    for (int mt = 0; mt < 4; ++mt)
        #pragma unroll
        for (int nt = 0; nt < 4; ++nt) {
            acc2[mt][nt][0] = 0.f; acc2[mt][nt][1] = 0.f;
            acc2[mt][nt][2] = 0.f; acc2[mt][nt][3] = 0.f;
        }
    #pragma unroll
    for (int kc2 = 0; kc2 < 2; ++kc2) {
        s16x8 a2[4];
        #pragma unroll
        for (int mt = 0; mt < 4; ++mt)
            a2[mt] = *(const s16x8*)&hid[(w*64 + mt*16 + ln15)*HID_S + kc2*32 + oct*8];
        #pragma unroll
        for (int nt = 0; nt < 4; ++nt) {
            s16x8 bf = *(const s16x8*)(W2s + ((size_t)(kc2*4 + nt)*64 + lane)*8);
            #pragma unroll
            for (int mt = 0; mt < 4; ++mt)
                acc2[mt][nt] = __builtin_amdgcn_mfma_f32_16x16x32_bf16(a2[mt], bf, acc2[mt][nt], 0, 0, 0);
        }
    }

    float* ob = out + ((size_t)(b*128 + y))*128*64;
    #pragma unroll
    for (int nt = 0; nt < 4; ++nt) {
        const float b2v = b2[nt*16 + ln15];
        #pragma unroll
        for (int mt = 0; mt < 4; ++mt) {
            #pragma unroll
            for (int r = 0; r < 4; ++r) {
                int x = xw + mt*16 + oct*4 + r;
                ob[(size_t)x*64 + nt*16 + ln15] = acc2[mt][nt][r] + b2v;
            }
        }
    }
}

// ---------------- launch ----------------------------------------------------
extern "C" void kernel_launch(void* const* d_in, const int* in_sizes, int n_in,
                              void* d_out, int out_size, void* d_ws, size_t ws_size,
                              hipStream_t stream) {
    const float* x   = (const float*)d_in[0];
    const float* c   = (const float*)d_in[1];
    // d_in[2..5] = Wq,bq,Wk,bk : unused (softmax weights sum to 1 -> pool == v)
    const float* Wv  = (const float*)d_in[6];
    const float* bv  = (const float*)d_in[7];
    const float* Wo  = (const float*)d_in[8];
    const float* bo  = (const float*)d_in[9];
    const float* lng = (const float*)d_in[10];
    const float* lnb = (const float*)d_in[11];
    const float* pk  = (const float*)d_in[12];
    const float* W1  = (const float*)d_in[13];
    const float* b1  = (const float*)d_in[14];
    const float* W2  = (const float*)d_in[15];
    const float* b2  = (const float*)d_in[16];
    float* out = (float*)d_out;

    char* w = (char*)d_ws;
    unsigned short* xpb = (unsigned short*)(w);                  // 21,233,664 B (+4KB overrun slack)
    unsigned short* Uf  = (unsigned short*)(w + 21237760);       //    270,336 B (33*512 frags)
    unsigned short* W2s = (unsigned short*)(w + 21508096);       //      8,192 B
    float*          V   = (float*)         (w + 21516288);       //     73,728 B
    float*          hcp = (float*)         (w + 21590016);       //      2,048 B
    float*          c2f = (float*)         (w + 21592064);       //      2,048 B (end 21,594,112)

    prepA<<<1064, 256, 0, stream>>>(x, c, Wv, bv, Wo, bo, lng, lnb, xpb, c2f, out + 8388608);
    prepB<<<141, 256, 0, stream>>>(pk, W1, W2, b1, c2f, Uf, W2s, V, hcp);
    nca_main<<<512, 256, 0, stream>>>(xpb, Uf, W2s, V, hcp, b2, out);
}

// Round 8
// 167.817 us; speedup vs baseline: 1.3384x; 1.3384x over previous
//
#include <hip/hip_runtime.h>
#include <hip/hip_bf16.h>
#include <math.h>

// B=8, H=W=128, CH=64, OC=64, NCA_C=128, K=3, dils {1,2,4,8}, HID=64
// out: y [8,128,128,64] fp32 (8388608) then c2 [8,64] fp32 (512)
//
// Depthwise conv folded into GEMM1 over 33 positions (center-merged). Round-8:
// revert to the round-4 K-loop (global loads, register A dbuf, NO LDS, NO barriers
// -- every LDS-staging variant lost to spills/barriers/conflicts) and halve all
// K-loop bytes with fp8-e4m3: xpad fp8, U fp8 scaled x256 (else subnormal),
// mfma_f32_16x16x32_fp8_fp8 (same shape/rate/mapping as bf16). Const channels
// stay fp32 (hc2/Cx/Cy/V tables). Epilogue: h = acc/256 + tables. b=blk&7 XCD-local.

typedef float  f32x4 __attribute__((ext_vector_type(4)));
typedef short  s16x8 __attribute__((ext_vector_type(8)));
typedef long   i64;

static __device__ __forceinline__ unsigned short f2bf(float f) {
    __hip_bfloat16 h = __float2bfloat16(f);
    unsigned short u; __builtin_memcpy(&u, &h, 2); return u;
}
// pack 4 floats -> 4 fp8 e4m3 bytes (OCP, saturating)
static __device__ __forceinline__ unsigned pk4fp8(float f0, float f1, float f2, float f3) {
    int v = 0;
    v = __builtin_amdgcn_cvt_pk_fp8_f32(f0, f1, v, false);   // bytes 0,1
    v = __builtin_amdgcn_cvt_pk_fp8_f32(f2, f3, v, true);    // bytes 2,3
    return (unsigned)v;
}

// xpad layout (BYTES, fp8): [b][plane(4)=16ch][yy(144)][xx(144)][16ch]
#define XROW   2304
#define XPLANE 331776
#define XBATCH 1327104
#define USCALE 256.0f

// ---------------- prepA: x -> padded fp8, pad zero-fill, c2 -----------------
__global__ void prepA(const float* __restrict__ x, const float* __restrict__ c,
                      const float* __restrict__ Wv, const float* __restrict__ bv,
                      const float* __restrict__ Wo, const float* __restrict__ bo,
                      const float* __restrict__ lng, const float* __restrict__ lnb,
                      unsigned char* __restrict__ xp, float* __restrict__ c2f,
                      float* __restrict__ outc2)
{
    const int blk = blockIdx.x, tid = threadIdx.x;
    if (blk < 512) {
        int i = blk*256 + tid;               // one px per thread [0,131072)
        int xc = i & 127, y = (i >> 7) & 127, b = i >> 14;
        const float* src = x + (size_t)i*64;
        unsigned char* dstb = xp + ((size_t)b*4*144 + (y+8))*XROW + (xc+8)*16;
        #pragma unroll
        for (int p = 0; p < 4; ++p) {
            float4 f0 = *(const float4*)(src + p*16 + 0);
            float4 f1 = *(const float4*)(src + p*16 + 4);
            float4 f2 = *(const float4*)(src + p*16 + 8);
            float4 f3 = *(const float4*)(src + p*16 + 12);
            uint4 o;
            o.x = pk4fp8(f0.x, f0.y, f0.z, f0.w);
            o.y = pk4fp8(f1.x, f1.y, f1.z, f1.w);
            o.z = pk4fp8(f2.x, f2.y, f2.z, f2.w);
            o.w = pk4fp8(f3.x, f3.y, f3.z, f3.w);
            *(uint4*)(dstb + (size_t)p*XPLANE) = o;
        }
    } else if (blk < 1056) {
        int idx = (blk - 512)*256 + tid;     // [0,139264) pad px
        int bp = idx / 4352;                 // b*4+plane
        int r  = idx - bp*4352;
        int yy, xx;
        if (r < 2304) { int ry = r / 144; xx = r - ry*144; yy = (ry < 8) ? ry : 128 + ry; }
        else { int r2 = r - 2304; yy = 8 + (r2 >> 4); int xi = r2 & 15; xx = (xi < 8) ? xi : 128 + xi; }
        *(uint4*)(xp + ((size_t)bp*144 + yy)*XROW + xx*16) = make_uint4(0,0,0,0);
    } else {
        // c2 = c + LN(v@Wo + bo + c), v = c@Wv + bv  (softmax pool == v exactly)
        const int b = blk - 1056;
        __shared__ float sc[64], sv[64];
        const int j = tid;
        if (j < 64) sc[j] = c[b*64 + j];
        __syncthreads();
        if (j < 64) {
            float v = bv[j];
            for (int i = 0; i < 64; ++i) v += sc[i]*Wv[i*64 + j];
            sv[j] = v;
        }
        __syncthreads();
        if (j < 64) {
            float t = bo[j] + sc[j];
            for (int i = 0; i < 64; ++i) t += sv[i]*Wo[i*64 + j];
            float s = t;
            for (int o = 32; o > 0; o >>= 1) s += __shfl_xor(s, o);
            float m = s * (1.f/64.f);
            float dq = (t - m)*(t - m);
            for (int o = 32; o > 0; o >>= 1) dq += __shfl_xor(dq, o);
            float a = (t - m) / sqrtf(dq*(1.f/64.f) + 1e-5f) * lng[j] + lnb[j];
            float c2 = sc[j] + a;
            c2f[b*64 + j] = c2;
            outc2[b*64 + j] = c2;
        }
    }
}

// ---------------- prepB: U frags fp8 (33 pos), W2 bf16, V, hcp --------------
// pos order: rows dy=-8,-4,-2,-1 (dx=-d,0,+d); p12=merged center; p13..20 dy=0
// dx=+-1,+-2,+-4,+-8; rows dy=+1,+2,+4,+8. Frag: k=kc2*32+oct*8+j (data ch),
// n=nt*16+(lane&15). Values scaled x256 for fp8 range.
__global__ void prepB(const float* __restrict__ pk, const float* __restrict__ W1,
                      const float* __restrict__ W2, const float* __restrict__ b1,
                      const float* __restrict__ c2f,
                      unsigned char* __restrict__ Uf, unsigned short* __restrict__ W2s,
                      float* __restrict__ V, float* __restrict__ hcp)
{
    const int blk = blockIdx.x, tid = threadIdx.x;
    if (blk < 66) {
        int idx = blk*256 + tid;            // [0, 16896) = 33*512
        int lane = idx & 63, nt = (idx >> 6) & 3, kc2 = (idx >> 8) & 1, pos = idx >> 9;
        int n  = nt*16 + (lane & 15);
        int k0 = kc2*32 + (lane >> 4)*8;
        static constexpr int DI[33] = {3,3,3, 2,2,2, 1,1,1, 0,0,0, -1, 0,0, 1,1, 2,2, 3,3,
                                       0,0,0, 1,1,1, 2,2,2, 3,3,3};
        static constexpr int TT[33] = {0,1,2, 0,1,2, 0,1,2, 0,1,2, 4, 3,5, 3,5, 3,5, 3,5,
                                       6,7,8, 6,7,8, 6,7,8, 6,7,8};
        int di = DI[pos], t = TT[pos];
        float vv[8];
        #pragma unroll
        for (int j = 0; j < 8; ++j) {
            int ch = k0 + j;
            float v;
            if (di < 0) {                   // merged center: identity + 4 dil centers
                v = W1[ch*64 + n];
                for (int dd = 0; dd < 4; ++dd)
                    v += pk[(dd*128 + ch)*9 + 4] * W1[((1+dd)*128 + ch)*64 + n];
            } else {
                v = pk[(di*128 + ch)*9 + t] * W1[((1+di)*128 + ch)*64 + n];
            }
            vv[j] = v * USCALE;
        }
        uint2 o;
        o.x = pk4fp8(vv[0], vv[1], vv[2], vv[3]);
        o.y = pk4fp8(vv[4], vv[5], vv[6], vv[7]);
        *(uint2*)(Uf + (size_t)idx*8) = o;
    } else if (blk < 68) {
        int idx = (blk-66)*256 + tid;       // [0,512)
        int lane = idx & 63, nt = (idx >> 6) & 3, kc2 = (idx >> 8) & 1;
        int n  = nt*16 + (lane & 15);
        int k0 = kc2*32 + (lane >> 4)*8;
        unsigned short e[8];
        #pragma unroll
        for (int j = 0; j < 8; ++j) e[j] = f2bf(W2[(k0+j)*64 + n]);
        uint4 o;
        o.x = (unsigned)e[0] | ((unsigned)e[1] << 16);
        o.y = (unsigned)e[2] | ((unsigned)e[3] << 16);
        o.z = (unsigned)e[4] | ((unsigned)e[5] << 16);
        o.w = (unsigned)e[6] | ((unsigned)e[7] << 16);
        *(uint4*)(W2s + (size_t)idx*8) = o;
    } else if (blk < 140) {
        int idx = (blk-68)*256 + tid;       // [0, 18432) = 8*36*64
        int n = idx & 63, q = idx >> 6;     // q = b*36 + p
        int p = q % 36, b = q / 36;
        int di = p/9, t = p%9;
        float s = 0.f;
        for (int j = 0; j < 64; ++j)
            s += c2f[b*64 + j] * pk[(di*128 + 64 + j)*9 + t] * W1[((1+di)*128 + 64 + j)*64 + n];
        V[(size_t)q*64 + n] = s;
    } else {
        for (int it = tid; it < 512; it += 256) {
            int b = it >> 6, n = it & 63;
            float s = b1[n];
            for (int j = 0; j < 64; ++j) s += c2f[b*64 + j]*W1[(64 + j)*64 + n];
            hcp[it] = s;
        }
    }
}

// ---------------- main fused kernel -----------------------------------------
#define HID_S 72

__global__ __launch_bounds__(256) void nca_main(
    const unsigned char* __restrict__ xp,
    const unsigned char* __restrict__ U,
    const unsigned short* __restrict__ W2s,
    const float* __restrict__ V,
    const float* __restrict__ hcp,
    const float* __restrict__ b2,
    float* __restrict__ out)
{
    __shared__ unsigned short hid[256*HID_S]; // 36864 B
    __shared__ float V_l[36*64];              //  9216 B
    __shared__ float Cx_l[16*64];             //  4096 B
    __shared__ float Cy_l[2*64];              //   512 B
    __shared__ float hc2_l[64];               //   256 B  -> ~51 KB

    const int tid = threadIdx.x;
    const int blk = blockIdx.x;
    const int b  = blk & 7;                   // XCD-local batch
    const int y0 = (blk >> 3) * 2;

    // ---- tables ----
    {
        const float4* Vg = (const float4*)(V + (size_t)b*2304);
        for (int i = tid; i < 576; i += 256) ((float4*)V_l)[i] = Vg[i];
    }
    __syncthreads();
    for (int it = tid; it < 1024; it += 256) {      // Cx: x-edge correction
        int xi = it >> 6, n = it & 63;
        int xx = xi < 8 ? xi : 112 + xi;
        float s = 0.f;
        #pragma unroll
        for (int di = 0; di < 4; ++di) {
            int d = 1 << di;
            int dxo = (xx < d) ? 0 : ((xx >= 128 - d) ? 2 : -1);
            if (dxo >= 0) {
                s += V_l[(di*9 + 0*3 + dxo)*64 + n];
                s += V_l[(di*9 + 1*3 + dxo)*64 + n];
                s += V_l[(di*9 + 2*3 + dxo)*64 + n];
            }
        }
        Cx_l[it] = s;
    }
    for (int it = tid; it < 128; it += 256) {       // Cy for this block's 2 rows
        int r = it >> 6, n = it & 63;
        int yy = y0 + r;
        float s = 0.f;
        #pragma unroll
        for (int di = 0; di < 4; ++di) {
            int d = 1 << di;
            int dyo = (yy < d) ? 0 : ((yy >= 128 - d) ? 2 : -1);
            if (dyo >= 0) {
                s += V_l[(di*9 + dyo*3 + 0)*64 + n];
                s += V_l[(di*9 + dyo*3 + 1)*64 + n];
                s += V_l[(di*9 + dyo*3 + 2)*64 + n];
            }
        }
        Cy_l[it] = s;
    }
    if (tid < 64) {
        float s = hcp[b*64 + tid];
        for (int p = 0; p < 36; ++p) s += V_l[p*64 + tid];
        hc2_l[tid] = s;
    }
    __syncthreads();

    // ---- geometry ----
    const int lane = tid & 63;
    const int w    = tid >> 6;          // wave: row = y0 + (w>>1), x-half = (w&1)*64
    const int y    = y0 + (w >> 1);
    const int xw   = (w & 1) * 64;
    const int ln15 = lane & 15;
    const int oct  = lane >> 4;

    // per-lane base (bytes): plane = (oct>>1), byte-in-px = (oct&1)*8; 8 ch per lane
    const unsigned char* base0 = xp + (size_t)b*XBATCH + (size_t)(oct >> 1)*XPLANE
                               + (size_t)(y + 8)*XROW + (size_t)(xw + ln15 + 8)*16
                               + (oct & 1)*8;

    f32x4 acc[4][4];
    #pragma unroll
    for (int mt = 0; mt < 4; ++mt)
        #pragma unroll
        for (int nt = 0; nt < 4; ++nt) {
            acc[mt][nt][0] = 0.f; acc[mt][nt][1] = 0.f;
            acc[mt][nt][2] = 0.f; acc[mt][nt][3] = 0.f;
        }

    // byte offsets (px stride 16 B), order matches prepB pos order
    static constexpr int OFF[33] = {
        (-8*144-8)*16, (-8*144)*16, (-8*144+8)*16,
        (-4*144-4)*16, (-4*144)*16, (-4*144+4)*16,
        (-2*144-2)*16, (-2*144)*16, (-2*144+2)*16,
        (-1*144-1)*16, (-1*144)*16, (-1*144+1)*16,
        0,
        -1*16, 1*16, -2*16, 2*16, -4*16, 4*16, -8*16, 8*16,
        ( 1*144-1)*16, ( 1*144)*16, ( 1*144+1)*16,
        ( 2*144-2)*16, ( 2*144)*16, ( 2*144+2)*16,
        ( 4*144-4)*16, ( 4*144)*16, ( 4*144+4)*16,
        ( 8*144-8)*16, ( 8*144)*16, ( 8*144+8)*16
    };

    // A register double-buffer (8 B per fragment)
    i64 avc[2][4];
    #pragma unroll
    for (int kc2 = 0; kc2 < 2; ++kc2)
        #pragma unroll
        for (int mt = 0; mt < 4; ++mt)
            avc[kc2][mt] = *(const i64*)(base0 + OFF[0] + kc2*(2*XPLANE) + mt*256);

    #pragma unroll 1
    for (int pos = 0; pos < 33; ++pos) {
        i64 avn[2][4];
        if (pos < 32) {
            const unsigned char* rp = base0 + OFF[pos + 1];
            #pragma unroll
            for (int kc2 = 0; kc2 < 2; ++kc2)
                #pragma unroll
                for (int mt = 0; mt < 4; ++mt)
                    avn[kc2][mt] = *(const i64*)(rp + kc2*(2*XPLANE) + mt*256);
        }
        const unsigned char* Up = U + (size_t)pos*4096 + lane*8;
        #pragma unroll
        for (int kc2 = 0; kc2 < 2; ++kc2) {
            #pragma unroll
            for (int nt = 0; nt < 4; ++nt) {
                i64 bf = *(const i64*)(Up + kc2*2048 + nt*512);
                #pragma unroll
                for (int mt = 0; mt < 4; ++mt)
                    acc[mt][nt] = __builtin_amdgcn_mfma_f32_16x16x32_fp8_fp8(avc[kc2][mt], bf, acc[mt][nt], 0, 0, 0);
            }
        }
        #pragma unroll
        for (int kc2 = 0; kc2 < 2; ++kc2)
            #pragma unroll
            for (int mt = 0; mt < 4; ++mt)
                avc[kc2][mt] = avn[kc2][mt];
    }

    // ---- epilogue 1: acc/256 + hc2 - corrections, GELU, write hid (bf16) ----
    const bool yedge = (y < 8) || (y >= 120);
    #pragma unroll
    for (int mt = 0; mt < 4; ++mt) {
        #pragma unroll
        for (int nt = 0; nt < 4; ++nt) {
            const int n = nt*16 + ln15;
            const float hcv = hc2_l[n];
            const float cyv = yedge ? Cy_l[(w >> 1)*64 + n] : 0.f;
            #pragma unroll
            for (int r = 0; r < 4; ++r) {
                int m = oct*4 + r;                  // C row = (lane>>4)*4 + reg
                int x = xw + mt*16 + m;
                float h = acc[mt][nt][r]*(1.0f/USCALE) + hcv - cyv;
                if (x < 8 || x >= 120) {
                    int xi = (x < 8) ? x : (x - 112);
                    h -= Cx_l[xi*64 + n];
                    if (yedge) {                    // corner double-subtract fix
                        #pragma unroll
                        for (int di = 0; di < 4; ++di) {
                            int d = 1 << di;
                            int dyo = (y < d) ? 0 : ((y >= 128 - d) ? 2 : -1);
                            int dxo = (x < d) ? 0 : ((x >= 128 - d) ? 2 : -1);
                            if (dyo >= 0 && dxo >= 0)
                                h += V_l[(di*9 + dyo*3 + dxo)*64 + n];
                        }
                    }
                }
                float u = 0.7978845608028654f * (h + 0.044715f*h*h*h);
                float g = h / (1.f + __expf(-2.f*u));
                hid[(w*64 + mt*16 + m)*HID_S + n] = f2bf(g);
            }
        }
    }
    // each wave reads back only its own 64 hid rows -> no barrier needed

    // ---- GEMM2: y = hid @ W2 + b2 (bf16) ----
    f32x4 acc2[4][4];
    #pragma unroll
    for (int mt = 0; mt < 4; ++mt)
        #pragma unroll
        for (int nt = 0; nt < 4; ++nt) {
            acc2[mt][nt][0] = 0.f; acc2[mt][nt][1] = 0.f;
            acc2[mt][nt][2] = 0.f; acc2[mt][nt][3] = 0.f;
        }
    #pragma unroll
    for (int kc2 = 0; kc2 < 2; ++kc2) {
        s16x8 a2[4];
        #pragma unroll
        for (int mt = 0; mt < 4; ++mt)
            a2[mt] = *(const s16x8*)&hid[(w*64 + mt*16 + ln15)*HID_S + kc2*32 + oct*8];
        #pragma unroll
        for (int nt = 0; nt < 4; ++nt) {
            s16x8 bf = *(const s16x8*)(W2s + ((size_t)(kc2*4 + nt)*64 + lane)*8);
            #pragma unroll
            for (int mt = 0; mt < 4; ++mt)
                acc2[mt][nt] = __builtin_amdgcn_mfma_f32_16x16x32_bf16(a2[mt], bf, acc2[mt][nt], 0, 0, 0);
        }
    }

    float* ob = out + ((size_t)(b*128 + y))*128*64;
    #pragma unroll
    for (int nt = 0; nt < 4; ++nt) {
        const float b2v = b2[nt*16 + ln15];
        #pragma unroll
        for (int mt = 0; mt < 4; ++mt) {
            #pragma unroll
            for (int r = 0; r < 4; ++r) {
                int x = xw + mt*16 + oct*4 + r;
                ob[(size_t)x*64 + nt*16 + ln15] = acc2[mt][nt][r] + b2v;
            }
        }
    }
}

// ---------------- launch ----------------------------------------------------
extern "C" void kernel_launch(void* const* d_in, const int* in_sizes, int n_in,
                              void* d_out, int out_size, void* d_ws, size_t ws_size,
                              hipStream_t stream) {
    const float* x   = (const float*)d_in[0];
    const float* c   = (const float*)d_in[1];
    // d_in[2..5] = Wq,bq,Wk,bk : unused (softmax weights sum to 1 -> pool == v)
    const float* Wv  = (const float*)d_in[6];
    const float* bv  = (const float*)d_in[7];
    const float* Wo  = (const float*)d_in[8];
    const float* bo  = (const float*)d_in[9];
    const float* lng = (const float*)d_in[10];
    const float* lnb = (const float*)d_in[11];
    const float* pk  = (const float*)d_in[12];
    const float* W1  = (const float*)d_in[13];
    const float* b1  = (const float*)d_in[14];
    const float* W2  = (const float*)d_in[15];
    const float* b2  = (const float*)d_in[16];
    float* out = (float*)d_out;

    char* w = (char*)d_ws;
    unsigned char*  xpb = (unsigned char*)(w);                   // 10,616,832 B
    unsigned char*  Uf  = (unsigned char*)(w + 10616832);        //    135,168 B
    unsigned short* W2s = (unsigned short*)(w + 10752000);       //      8,192 B
    float*          V   = (float*)         (w + 10760192);       //     73,728 B
    float*          hcp = (float*)         (w + 10833920);       //      2,048 B
    float*          c2f = (float*)         (w + 10835968);       //      2,048 B (end 10,838,016)

    prepA<<<1064, 256, 0, stream>>>(x, c, Wv, bv, Wo, bo, lng, lnb, xpb, c2f, out + 8388608);
    prepB<<<141, 256, 0, stream>>>(pk, W1, W2, b1, c2f, Uf, W2s, V, hcp);
    nca_main<<<512, 256, 0, stream>>>(xpb, Uf, W2s, V, hcp, b2, out);
}

// Round 9
// 162.558 us; speedup vs baseline: 1.3816x; 1.0324x over previous
//
#include <hip/hip_runtime.h>
#include <hip/hip_bf16.h>
#include <math.h>

// B=8, H=W=128, CH=64, OC=64, NCA_C=128, K=3, dils {1,2,4,8}, HID=64
// out: y [8,128,128,64] fp32 (8388608) then c2 [8,64] fp32 (512)
//
// Depthwise conv folded into GEMM1 over 33 positions (center-merged), fp8-e4m3
// (U scaled x256). Round-9: dwordx4 operands + full software pipeline.
//  - xpad: px-contiguous 64 B, byte order oct*16+kc2*8+j -> one dwordx4 per mt
//    gives both kc2 A-fragments (4 A loads/pos, perfectly coalesced 1024 B/wave).
//  - U: lane stride 16 B (kc2-interleaved) -> 4 B loads/pos.
//  - A AND B register double-buffered distance 1 (round 8 left B unprefetched:
//    bare ~200cyc dependency per position).
// NO LDS / NO barriers in K-loop (rounds 5-7: spills/barriers/conflicts all lose).
// b = blk&7 -> XCD-local L2.

typedef float  f32x4 __attribute__((ext_vector_type(4)));
typedef short  s16x8 __attribute__((ext_vector_type(8)));
typedef long   i64x2 __attribute__((ext_vector_type(2)));

static __device__ __forceinline__ unsigned short f2bf(float f) {
    __hip_bfloat16 h = __float2bfloat16(f);
    unsigned short u; __builtin_memcpy(&u, &h, 2); return u;
}
static __device__ __forceinline__ unsigned pk4fp8(float f0, float f1, float f2, float f3) {
    int v = 0;
    v = __builtin_amdgcn_cvt_pk_fp8_f32(f0, f1, v, false);
    v = __builtin_amdgcn_cvt_pk_fp8_f32(f2, f3, v, true);
    return (unsigned)v;
}

// xpad layout (fp8): [b][yy(144)][xx(144)][64 B: byte oct*16+kc2*8+j = ch kc2*32+oct*8+j]
#define XROWB  9216
#define XBATCH 1327104
#define USCALE 256.0f

// ---------------- prep1: c2 only (tiny) -------------------------------------
__global__ void prep1(const float* __restrict__ c,
                      const float* __restrict__ Wv, const float* __restrict__ bv,
                      const float* __restrict__ Wo, const float* __restrict__ bo,
                      const float* __restrict__ lng, const float* __restrict__ lnb,
                      float* __restrict__ c2f, float* __restrict__ outc2)
{
    const int b = blockIdx.x, j = threadIdx.x;
    __shared__ float sc[64], sv[64];
    float cj = c[b*64 + j];
    sc[j] = cj; __syncthreads();
    float v = bv[j];
    for (int i = 0; i < 64; ++i) v += sc[i]*Wv[i*64 + j];
    sv[j] = v; __syncthreads();
    float t = bo[j] + cj;
    for (int i = 0; i < 64; ++i) t += sv[i]*Wo[i*64 + j];
    float s = t;
    for (int o = 32; o > 0; o >>= 1) s += __shfl_xor(s, o);
    float m = s * (1.f/64.f);
    float dq = (t - m)*(t - m);
    for (int o = 32; o > 0; o >>= 1) dq += __shfl_xor(dq, o);
    float a = (t - m) / sqrtf(dq*(1.f/64.f) + 1e-5f) * lng[j] + lnb[j];
    float c2 = cj + a;
    c2f[b*64 + j] = c2;
    outc2[b*64 + j] = c2;
}

// ---------------- prep2: xpad + pad + U + W2s + V + hcp (one grid) ----------
__global__ void prep2(const float* __restrict__ x,  const float* __restrict__ pk,
                      const float* __restrict__ W1, const float* __restrict__ W2,
                      const float* __restrict__ b1, const float* __restrict__ c2f,
                      unsigned char* __restrict__ xp, unsigned char* __restrict__ Uf,
                      unsigned short* __restrict__ W2s,
                      float* __restrict__ V, float* __restrict__ hcp)
{
    const int blk = blockIdx.x, tid = threadIdx.x;
    if (blk < 512) {
        // convert: one px per thread; byte order oct*16 + kc2*8 + j
        int i = blk*256 + tid;
        int xc = i & 127, y = (i >> 7) & 127, b = i >> 14;
        const float* src = x + (size_t)i*64;
        float4 f[16];
        #pragma unroll
        for (int k = 0; k < 16; ++k) f[k] = *(const float4*)(src + k*4);
        unsigned P[16];
        #pragma unroll
        for (int k = 0; k < 16; ++k) P[k] = pk4fp8(f[k].x, f[k].y, f[k].z, f[k].w);
        unsigned char* d = xp + (size_t)b*XBATCH + (size_t)(y+8)*XROWB + (size_t)(xc+8)*64;
        *(uint4*)(d +  0) = make_uint4(P[0], P[1], P[8],  P[9]);   // oct0: ch0-7, ch32-39
        *(uint4*)(d + 16) = make_uint4(P[2], P[3], P[10], P[11]);  // oct1: ch8-15, ch40-47
        *(uint4*)(d + 32) = make_uint4(P[4], P[5], P[12], P[13]);  // oct2
        *(uint4*)(d + 48) = make_uint4(P[6], P[7], P[14], P[15]);  // oct3
    } else if (blk < 648) {
        int idx = (blk - 512)*256 + tid;     // [0,34816) pad px
        int b = idx / 4352, r = idx - b*4352;
        int yy, xx;
        if (r < 2304) { int ry = r / 144; xx = r - ry*144; yy = (ry < 8) ? ry : 128 + ry; }
        else { int r2 = r - 2304; yy = 8 + (r2 >> 4); int xi = r2 & 15; xx = (xi < 8) ? xi : 128 + xi; }
        unsigned char* d = xp + (size_t)b*XBATCH + (size_t)yy*XROWB + (size_t)xx*64;
        uint4 z = make_uint4(0,0,0,0);
        *(uint4*)(d) = z; *(uint4*)(d+16) = z; *(uint4*)(d+32) = z; *(uint4*)(d+48) = z;
    } else if (blk < 681) {
        // U frags: idx = (pos*4 + nt)*64 + lane; 16 B per entry (kc2 0 | kc2 1)
        int idx = (blk - 648)*256 + tid;     // [0, 8448) = 33*4*64
        if (idx < 8448) {
            int lane = idx & 63, nt = (idx >> 6) & 3, pos = idx >> 8;
            int n  = nt*16 + (lane & 15);
            static constexpr int DI[33] = {3,3,3, 2,2,2, 1,1,1, 0,0,0, -1, 0,0, 1,1, 2,2, 3,3,
                                           0,0,0, 1,1,1, 2,2,2, 3,3,3};
            static constexpr int TT[33] = {0,1,2, 0,1,2, 0,1,2, 0,1,2, 4, 3,5, 3,5, 3,5, 3,5,
                                           6,7,8, 6,7,8, 6,7,8, 6,7,8};
            int di = DI[pos], t = TT[pos];
            float vv[16];
            #pragma unroll
            for (int kc2 = 0; kc2 < 2; ++kc2)
                #pragma unroll
                for (int j = 0; j < 8; ++j) {
                    int ch = kc2*32 + (lane >> 4)*8 + j;
                    float v;
                    if (di < 0) {               // merged center
                        v = W1[ch*64 + n];
                        for (int dd = 0; dd < 4; ++dd)
                            v += pk[(dd*128 + ch)*9 + 4] * W1[((1+dd)*128 + ch)*64 + n];
                    } else {
                        v = pk[(di*128 + ch)*9 + t] * W1[((1+di)*128 + ch)*64 + n];
                    }
                    vv[kc2*8 + j] = v * USCALE;
                }
            uint4 o;
            o.x = pk4fp8(vv[0],  vv[1],  vv[2],  vv[3]);
            o.y = pk4fp8(vv[4],  vv[5],  vv[6],  vv[7]);
            o.z = pk4fp8(vv[8],  vv[9],  vv[10], vv[11]);
            o.w = pk4fp8(vv[12], vv[13], vv[14], vv[15]);
            *(uint4*)(Uf + (size_t)idx*16) = o;
        }
    } else if (blk < 683) {
        int idx = (blk - 681)*256 + tid;     // [0,512)
        int lane = idx & 63, nt = (idx >> 6) & 3, kc2 = (idx >> 8) & 1;
        int n  = nt*16 + (lane & 15);
        int k0 = kc2*32 + (lane >> 4)*8;
        unsigned short e[8];
        #pragma unroll
        for (int j = 0; j < 8; ++j) e[j] = f2bf(W2[(k0+j)*64 + n]);
        uint4 o;
        o.x = (unsigned)e[0] | ((unsigned)e[1] << 16);
        o.y = (unsigned)e[2] | ((unsigned)e[3] << 16);
        o.z = (unsigned)e[4] | ((unsigned)e[5] << 16);
        o.w = (unsigned)e[6] | ((unsigned)e[7] << 16);
        *(uint4*)(W2s + (size_t)idx*8) = o;
    } else if (blk < 755) {
        int idx = (blk - 683)*256 + tid;     // [0, 18432) = 8*36*64
        int n = idx & 63, q = idx >> 6;
        int p = q % 36, b = q / 36;
        int di = p/9, t = p%9;
        float s = 0.f;
        for (int j = 0; j < 64; ++j)
            s += c2f[b*64 + j] * pk[(di*128 + 64 + j)*9 + t] * W1[((1+di)*128 + 64 + j)*64 + n];
        V[(size_t)q*64 + n] = s;
    } else {
        for (int it = tid; it < 512; it += 256) {
            int b = it >> 6, n = it & 63;
            float s = b1[n];
            for (int j = 0; j < 64; ++j) s += c2f[b*64 + j]*W1[(64 + j)*64 + n];
            hcp[it] = s;
        }
    }
}

// ---------------- main fused kernel -----------------------------------------
#define HID_S 72

__global__ __launch_bounds__(256) void nca_main(
    const unsigned char* __restrict__ xp,
    const unsigned char* __restrict__ U,
    const unsigned short* __restrict__ W2s,
    const float* __restrict__ V,
    const float* __restrict__ hcp,
    const float* __restrict__ b2,
    float* __restrict__ out)
{
    __shared__ unsigned short hid[256*HID_S]; // 36864 B
    __shared__ float V_l[36*64];              //  9216 B
    __shared__ float Cx_l[16*64];             //  4096 B
    __shared__ float Cy_l[2*64];              //   512 B
    __shared__ float hc2_l[64];               //   256 B  -> ~51 KB

    const int tid = threadIdx.x;
    const int blk = blockIdx.x;
    const int b  = blk & 7;                   // XCD-local batch
    const int y0 = (blk >> 3) * 2;

    // ---- tables ----
    {
        const float4* Vg = (const float4*)(V + (size_t)b*2304);
        for (int i = tid; i < 576; i += 256) ((float4*)V_l)[i] = Vg[i];
    }
    __syncthreads();
    for (int it = tid; it < 1024; it += 256) {      // Cx: x-edge correction
        int xi = it >> 6, n = it & 63;
        int xx = xi < 8 ? xi : 112 + xi;
        float s = 0.f;
        #pragma unroll
        for (int di = 0; di < 4; ++di) {
            int d = 1 << di;
            int dxo = (xx < d) ? 0 : ((xx >= 128 - d) ? 2 : -1);
            if (dxo >= 0) {
                s += V_l[(di*9 + 0*3 + dxo)*64 + n];
                s += V_l[(di*9 + 1*3 + dxo)*64 + n];
                s += V_l[(di*9 + 2*3 + dxo)*64 + n];
            }
        }
        Cx_l[it] = s;
    }
    for (int it = tid; it < 128; it += 256) {       // Cy for this block's 2 rows
        int r = it >> 6, n = it & 63;
        int yy = y0 + r;
        float s = 0.f;
        #pragma unroll
        for (int di = 0; di < 4; ++di) {
            int d = 1 << di;
            int dyo = (yy < d) ? 0 : ((yy >= 128 - d) ? 2 : -1);
            if (dyo >= 0) {
                s += V_l[(di*9 + dyo*3 + 0)*64 + n];
                s += V_l[(di*9 + dyo*3 + 1)*64 + n];
                s += V_l[(di*9 + dyo*3 + 2)*64 + n];
            }
        }
        Cy_l[it] = s;
    }
    if (tid < 64) {
        float s = hcp[b*64 + tid];
        for (int p = 0; p < 36; ++p) s += V_l[p*64 + tid];
        hc2_l[tid] = s;
    }
    __syncthreads();

    // ---- geometry ----
    const int lane = tid & 63;
    const int w    = tid >> 6;          // wave: row = y0 + (w>>1), x-half = (w&1)*64
    const int y    = y0 + (w >> 1);
    const int xw   = (w & 1) * 64;
    const int ln15 = lane & 15;
    const int oct  = lane >> 4;

    // A: one dwordx4 per mt = both kc2 fragments (bytes oct*16..+15 of the px)
    const unsigned char* abase = xp + (size_t)b*XBATCH + (size_t)(y + 8)*XROWB
                               + (size_t)(xw + ln15 + 8)*64 + oct*16;
    const unsigned char* ubase = U + (size_t)lane*16;

    f32x4 acc[4][4];
    #pragma unroll
    for (int mt = 0; mt < 4; ++mt)
        #pragma unroll
        for (int nt = 0; nt < 4; ++nt) {
            acc[mt][nt][0] = 0.f; acc[mt][nt][1] = 0.f;
            acc[mt][nt][2] = 0.f; acc[mt][nt][3] = 0.f;
        }

    // byte offsets (px stride 64 B), order matches prep2 U pos order
    static constexpr int OFF[33] = {
        (-8*144-8)*64, (-8*144)*64, (-8*144+8)*64,
        (-4*144-4)*64, (-4*144)*64, (-4*144+4)*64,
        (-2*144-2)*64, (-2*144)*64, (-2*144+2)*64,
        (-1*144-1)*64, (-1*144)*64, (-1*144+1)*64,
        0,
        -64, 64, -128, 128, -256, 256, -512, 512,
        ( 1*144-1)*64, ( 1*144)*64, ( 1*144+1)*64,
        ( 2*144-2)*64, ( 2*144)*64, ( 2*144+2)*64,
        ( 4*144-4)*64, ( 4*144)*64, ( 4*144+4)*64,
        ( 8*144-8)*64, ( 8*144)*64, ( 8*144+8)*64
    };

    // A and B register double-buffers, distance 1
    i64x2 Ac[4], An[4], Bc[4], Bn[4];
    #pragma unroll
    for (int mt = 0; mt < 4; ++mt) Ac[mt] = *(const i64x2*)(abase + OFF[0] + mt*1024);
    #pragma unroll
    for (int nt = 0; nt < 4; ++nt) Bc[nt] = *(const i64x2*)(ubase + nt*1024);

    #pragma unroll 1
    for (int pos = 0; pos < 33; ++pos) {
        if (pos < 32) {
            const unsigned char* rp = abase + OFF[pos + 1];
            #pragma unroll
            for (int mt = 0; mt < 4; ++mt) An[mt] = *(const i64x2*)(rp + mt*1024);
            const unsigned char* up = ubase + (size_t)(pos + 1)*4096;
            #pragma unroll
            for (int nt = 0; nt < 4; ++nt) Bn[nt] = *(const i64x2*)(up + nt*1024);
        }
        #pragma unroll
        for (int kc2 = 0; kc2 < 2; ++kc2) {
            #pragma unroll
            for (int nt = 0; nt < 4; ++nt) {
                long bf = Bc[nt][kc2];
                #pragma unroll
                for (int mt = 0; mt < 4; ++mt)
                    acc[mt][nt] = __builtin_amdgcn_mfma_f32_16x16x32_fp8_fp8(Ac[mt][kc2], bf, acc[mt][nt], 0, 0, 0);
            }
        }
        #pragma unroll
        for (int mt = 0; mt < 4; ++mt) Ac[mt] = An[mt];
        #pragma unroll
        for (int nt = 0; nt < 4; ++nt) Bc[nt] = Bn[nt];
    }

    // ---- epilogue 1: acc/256 + hc2 - corrections, GELU, write hid (bf16) ----
    const bool yedge = (y < 8) || (y >= 120);
    #pragma unroll
    for (int mt = 0; mt < 4; ++mt) {
        #pragma unroll
        for (int nt = 0; nt < 4; ++nt) {
            const int n = nt*16 + ln15;
            const float hcv = hc2_l[n];
            const float cyv = yedge ? Cy_l[(w >> 1)*64 + n] : 0.f;
            #pragma unroll
            for (int r = 0; r < 4; ++r) {
                int m = oct*4 + r;                  // C row = (lane>>4)*4 + reg
                int x = xw + mt*16 + m;
                float h = acc[mt][nt][r]*(1.0f/USCALE) + hcv - cyv;
                if (x < 8 || x >= 120) {
                    int xi = (x < 8) ? x : (x - 112);
                    h -= Cx_l[xi*64 + n];
                    if (yedge) {                    // corner double-subtract fix
                        #pragma unroll
                        for (int di = 0; di < 4; ++di) {
                            int d = 1 << di;
                            int dyo = (y < d) ? 0 : ((y >= 128 - d) ? 2 : -1);
                            int dxo = (x < d) ? 0 : ((x >= 128 - d) ? 2 : -1);
                            if (dyo >= 0 && dxo >= 0)
                                h += V_l[(di*9 + dyo*3 + dxo)*64 + n];
                        }
                    }
                }
                float u = 0.7978845608028654f * (h + 0.044715f*h*h*h);
                float g = h / (1.f + __expf(-2.f*u));
                hid[(w*64 + mt*16 + m)*HID_S + n] = f2bf(g);
            }
        }
    }
    // each wave reads back only its own 64 hid rows -> no barrier needed

    // ---- GEMM2: y = hid @ W2 + b2 (bf16) ----
    f32x4 acc2[4][4];
    #pragma unroll
    for (int mt = 0; mt < 4; ++mt)
        #pragma unroll
        for (int nt = 0; nt < 4; ++nt) {
            acc2[mt][nt][0] = 0.f; acc2[mt][nt][1] = 0.f;
            acc2[mt][nt][2] = 0.f; acc2[mt][nt][3] = 0.f;
        }
    #pragma unroll
    for (int kc2 = 0; kc2 < 2; ++kc2) {
        s16x8 a2[4];
        #pragma unroll
        for (int mt = 0; mt < 4; ++mt)
            a2[mt] = *(const s16x8*)&hid[(w*64 + mt*16 + ln15)*HID_S + kc2*32 + oct*8];
        #pragma unroll
        for (int nt = 0; nt < 4; ++nt) {
            s16x8 bf = *(const s16x8*)(W2s + ((size_t)(kc2*4 + nt)*64 + lane)*8);
            #pragma unroll
            for (int mt = 0; mt < 4; ++mt)
                acc2[mt][nt] = __builtin_amdgcn_mfma_f32_16x16x32_bf16(a2[mt], bf, acc2[mt][nt], 0, 0, 0);
        }
    }

    float* ob = out + ((size_t)(b*128 + y))*128*64;
    #pragma unroll
    for (int nt = 0; nt < 4; ++nt) {
        const float b2v = b2[nt*16 + ln15];
        #pragma unroll
        for (int mt = 0; mt < 4; ++mt) {
            #pragma unroll
            for (int r = 0; r < 4; ++r) {
                int x = xw + mt*16 + oct*4 + r;
                ob[(size_t)x*64 + nt*16 + ln15] = acc2[mt][nt][r] + b2v;
            }
        }
    }
}

// ---------------- launch ----------------------------------------------------
extern "C" void kernel_launch(void* const* d_in, const int* in_sizes, int n_in,
                              void* d_out, int out_size, void* d_ws, size_t ws_size,
                              hipStream_t stream) {
    const float* x   = (const float*)d_in[0];
    const float* c   = (const float*)d_in[1];
    // d_in[2..5] = Wq,bq,Wk,bk : unused (softmax weights sum to 1 -> pool == v)
    const float* Wv  = (const float*)d_in[6];
    const float* bv  = (const float*)d_in[7];
    const float* Wo  = (const float*)d_in[8];
    const float* bo  = (const float*)d_in[9];
    const float* lng = (const float*)d_in[10];
    const float* lnb = (const float*)d_in[11];
    const float* pk  = (const float*)d_in[12];
    const float* W1  = (const float*)d_in[13];
    const float* b1  = (const float*)d_in[14];
    const float* W2  = (const float*)d_in[15];
    const float* b2  = (const float*)d_in[16];
    float* out = (float*)d_out;

    char* w = (char*)d_ws;
    unsigned char*  xpb = (unsigned char*)(w);                   // 10,616,832 B
    unsigned char*  Uf  = (unsigned char*)(w + 10616832);        //    135,168 B
    unsigned short* W2s = (unsigned short*)(w + 10752000);       //      8,192 B
    float*          V   = (float*)         (w + 10760192);       //     73,728 B
    float*          hcp = (float*)         (w + 10833920);       //      2,048 B
    float*          c2f = (float*)         (w + 10835968);       //      2,048 B (end 10,838,016)

    prep1<<<8, 64, 0, stream>>>(c, Wv, bv, Wo, bo, lng, lnb, c2f, out + 8388608);
    prep2<<<757, 256, 0, stream>>>(x, pk, W1, W2, b1, c2f, xpb, Uf, W2s, V, hcp);
    nca_main<<<512, 256, 0, stream>>>(xpb, Uf, W2s, V, hcp, b2, out);
}